// Round 5
// baseline (831.804 us; speedup 1.0000x reference)
//
#include <hip/hip_runtime.h>
#include <hip/hip_bf16.h>

// Problem constants
#define B_SZ   64
#define N_IN   1024
#define D_IN   512
#define NC     32
#define DC     64

typedef unsigned short u16;

__device__ __forceinline__ float bf2f(u16 u) {
    unsigned x = ((unsigned)u) << 16;
    return __builtin_bit_cast(float, x);
}
__device__ __forceinline__ u16 f2bf(float f) {
    unsigned x = __builtin_bit_cast(unsigned, f);
    unsigned r = (x + 0x7fffu + ((x >> 16) & 1u)) >> 16;   // RNE
    return (u16)r;
}

// ---------------------------------------------------------------------------
// rowsum: Arow[b][k] = sum_i A[b,i,k]   (A fp32)
// grid 512 = 64 b x 8 chunks of 128 rows; atomicAdd into memset Arow.
// ---------------------------------------------------------------------------
__global__ __launch_bounds__(256) void rowsum_kernel(const float* __restrict__ A,
                                                     float* __restrict__ Arow) {
    const int tid = threadIdx.x;
    const int b  = blockIdx.x >> 3;
    const int r0 = (blockIdx.x & 7) << 7;
    const float* p = A + ((size_t)(b * N_IN + r0)) * 512 + tid * 2;
    float a0 = 0.f, a1 = 0.f;
    for (int r = 0; r < 128; ++r) {
        float2 v = *(const float2*)(p + (size_t)r * 512);
        a0 += v.x; a1 += v.y;
    }
    atomicAdd(&Arow[b * 512 + tid * 2], a0);
    atomicAdd(&Arow[b * 512 + tid * 2 + 1], a1);
}

// ---------------------------------------------------------------------------
// s0 + squash: s[b][z] = (1/32) sum_k Arow[b][k] W[k][z]; squash over d and
// write outs. Wave = 64 lanes = one capsule (z0 multiple of 256).
// ---------------------------------------------------------------------------
__global__ __launch_bounds__(256) void s0_squash(const float* __restrict__ Arow,
                                                 const float* __restrict__ W,
                                                 float* __restrict__ outs) {
    const int tid = threadIdx.x;
    const int b  = blockIdx.x >> 3;
    const int z0 = (blockIdx.x & 7) << 8;
    const int z  = z0 + tid;
    const float* ar = Arow + b * 512;          // uniform index -> s_load
    float acc = 0.f;
#pragma unroll 8
    for (int k = 0; k < 512; ++k) acc += ar[k] * W[(size_t)k * 2048 + z];
    acc *= 0.03125f;
    float sq = acc * acc;
    for (int off = 32; off; off >>= 1) sq += __shfl_xor(sq, off);
    float o = acc * (1.0f / sqrtf(sq + 1e-7f));
    outs[(size_t)b * 2048 + z] = o;
}

// ---------------------------------------------------------------------------
// G-kernel: G[b][k][n] = sum_d W[k][n*64+d] * outs[b][n*64+d]
// grid 256 = 64 b x 4 k-quarters. Lane = (kp, n); v for its capsule lives in
// 16 float4 registers; W float4 reads are L1-friendly (16 KB window).
// ---------------------------------------------------------------------------
__global__ __launch_bounds__(256) void g_kernel(const float* __restrict__ W,
                                                const float* __restrict__ outs,
                                                float* __restrict__ G) {
    const int tid  = threadIdx.x;
    const int b    = blockIdx.x >> 2;
    const int q    = blockIdx.x & 3;
    const int w    = __builtin_amdgcn_readfirstlane(tid >> 6);
    const int lane = tid & 63;
    const int kp   = lane >> 5;
    const int n    = lane & 31;

    float4 vr[16];
#pragma unroll
    for (int i = 0; i < 16; ++i)
        vr[i] = *(const float4*)(outs + (size_t)b * 2048 + n * 64 + i * 4);

    const int kbase = q * 128 + w * 32 + kp;
    for (int jj = 0; jj < 16; ++jj) {
        const int k = kbase + jj * 2;
        const float* wr = W + (size_t)k * 2048 + n * 64;
        float acc = 0.f;
#pragma unroll
        for (int dq = 0; dq < 16; ++dq) {
            float4 wv = *(const float4*)(wr + dq * 4);
            acc += wv.x * vr[dq].x + wv.y * vr[dq].y + wv.z * vr[dq].z + wv.w * vr[dq].w;
        }
        G[(size_t)b * 16384 + k * 32 + n] = acc;
    }
}

// ---------------------------------------------------------------------------
// routing_pass: one streaming pass over A per iteration.
// grid 256 = 64 b x 4 chunks of 256 rows; 4 stages of 64 rows each.
// Stage: load A rows -> bf16 LDS (stride 522: phase1/phase2 reads 2-way-free);
// phase1 logits (lane=row, wave=n-oct, G via uniform loads); softmax in LDS;
// phase2 Mp[n][k] += c^T A (thread = k-pair, c via LDS broadcast b128).
// ---------------------------------------------------------------------------
#define ASTRIDE 522
__global__ __launch_bounds__(256) void routing_pass(const float* __restrict__ A,
                                                    const float* __restrict__ G,
                                                    float* __restrict__ Mp) {
    __shared__ u16   Al[64 * ASTRIDE];
    __shared__ float cl[64 * 36];
    const int tid   = threadIdx.x;
    const int b     = blockIdx.x >> 2;
    const int chunk = blockIdx.x & 3;
    const int lane  = tid & 63;
    const int w     = __builtin_amdgcn_readfirstlane(tid >> 6);
    const float* Gb = G + (size_t)b * 16384;

    float macc[32][2];
#pragma unroll
    for (int n = 0; n < 32; ++n) { macc[n][0] = 0.f; macc[n][1] = 0.f; }

    for (int stage = 0; stage < 4; ++stage) {
        const int row0 = chunk * 256 + stage * 64;
        // ---- stage-load: 64 rows fp32 -> bf16 LDS ----
        const float* gsrc = A + ((size_t)(b * N_IN + row0)) * 512;
#pragma unroll
        for (int i = 0; i < 32; ++i) {
            int off = i * 1024 + tid * 4;
            float4 v = *(const float4*)(gsrc + off);
            int r = off >> 9, k = off & 511;
            unsigned p0 = (unsigned)f2bf(v.x) | ((unsigned)f2bf(v.y) << 16);
            unsigned p1 = (unsigned)f2bf(v.z) | ((unsigned)f2bf(v.w) << 16);
            *(unsigned*)&Al[r * ASTRIDE + k]     = p0;
            *(unsigned*)&Al[r * ASTRIDE + k + 2] = p1;
        }
        __syncthreads();

        // ---- phase1: logits[r=lane][n-oct w] ----
        float lacc[8];
#pragma unroll
        for (int nn = 0; nn < 8; ++nn) lacc[nn] = 0.f;
        const u16* arow = Al + lane * ASTRIDE;
        for (int jp = 0; jp < 256; ++jp) {
            unsigned a2 = *(const unsigned*)&arow[2 * jp];
            float a0 = bf2f((u16)(a2 & 0xffffu));
            float a1 = bf2f((u16)(a2 >> 16));
            const float* g0 = Gb + (2 * jp) * 32 + w * 8;   // uniform -> s_load
#pragma unroll
            for (int nn = 0; nn < 8; ++nn)
                lacc[nn] += a0 * g0[nn] + a1 * g0[32 + nn];
        }
#pragma unroll
        for (int nn = 0; nn < 8; ++nn) cl[lane * 36 + w * 8 + nn] = lacc[nn];
        __syncthreads();

        // ---- softmax over 32 capsules per row ----
        if (tid < 64) {
            float* row = &cl[tid * 36];
            float mx = row[0];
            for (int k = 1; k < NC; ++k) mx = fmaxf(mx, row[k]);
            float ssum = 0.f;
            for (int k = 0; k < NC; ++k) { float t = __expf(row[k] - mx); row[k] = t; ssum += t; }
            float inv = 1.f / ssum;
            for (int k = 0; k < NC; ++k) row[k] *= inv;
        }
        __syncthreads();

        // ---- phase2: Mp[n][k-pair tid] += sum_r c[r][n] * A[r][k] ----
        for (int r = 0; r < 64; ++r) {
            unsigned a2 = *(const unsigned*)&Al[r * ASTRIDE + 2 * tid];
            float a0 = bf2f((u16)(a2 & 0xffffu));
            float a1 = bf2f((u16)(a2 >> 16));
            const float* crow = &cl[r * 36];
#pragma unroll
            for (int nq = 0; nq < 8; ++nq) {
                float4 c4 = *(const float4*)(crow + nq * 4);   // broadcast
                macc[nq * 4 + 0][0] += c4.x * a0; macc[nq * 4 + 0][1] += c4.x * a1;
                macc[nq * 4 + 1][0] += c4.y * a0; macc[nq * 4 + 1][1] += c4.y * a1;
                macc[nq * 4 + 2][0] += c4.z * a0; macc[nq * 4 + 2][1] += c4.z * a1;
                macc[nq * 4 + 3][0] += c4.w * a0; macc[nq * 4 + 3][1] += c4.w * a1;
            }
        }
        __syncthreads();
    }

    // ---- write Mp partial: [b][chunk][32][512] ----
    float* mpb = Mp + (((size_t)b * 4 + chunk) * 32) * 512;
#pragma unroll
    for (int n = 0; n < 32; ++n) {
        float2 v = { macc[n][0], macc[n][1] };
        *(float2*)(mpb + (size_t)n * 512 + 2 * tid) = v;
    }
}

// ---------------------------------------------------------------------------
// s_squash: M = sum of 4 Mp slices; s[b,n,d] = sum_k M[k] W[k][n*64+d];
// squash over d; write outs (and final out on last iteration).
// grid 2048 = (b,n); 64 threads (one wave).
// ---------------------------------------------------------------------------
__global__ __launch_bounds__(64) void s_squash(const float* __restrict__ Mp,
                                               const float* __restrict__ W,
                                               float* __restrict__ outs,
                                               float* __restrict__ outf) {
    __shared__ float Ml[512];
    const int b = blockIdx.x >> 5;
    const int n = blockIdx.x & 31;
    const int d = threadIdx.x;

    // reduce 4 chunk-partials; lane d owns k = d*8..d*8+8
    {
        float4 s0 = {0,0,0,0}, s1 = {0,0,0,0};
#pragma unroll
        for (int c = 0; c < 4; ++c) {
            const float* p = Mp + (((size_t)b * 4 + c) * 32 + n) * 512 + d * 8;
            float4 v0 = *(const float4*)p;
            float4 v1 = *(const float4*)(p + 4);
            s0.x += v0.x; s0.y += v0.y; s0.z += v0.z; s0.w += v0.w;
            s1.x += v1.x; s1.y += v1.y; s1.z += v1.z; s1.w += v1.w;
        }
        *(float4*)&Ml[d * 8]     = s0;
        *(float4*)&Ml[d * 8 + 4] = s1;
    }
    __syncthreads();

    const float* wc = W + n * 64 + d;
    float acc = 0.f;
#pragma unroll 8
    for (int k = 0; k < 512; ++k) acc += Ml[k] * wc[(size_t)k * 2048];

    float sq = acc * acc;
    for (int off = 32; off; off >>= 1) sq += __shfl_xor(sq, off);
    float o = acc * (1.0f / sqrtf(sq + 1e-7f));
    size_t idx = (size_t)b * 2048 + n * 64 + d;
    outs[idx] = o;
    if (outf) outf[idx] = o;
}

// ---------------------------------------------------------------------------
extern "C" void kernel_launch(void* const* d_in, const int* in_sizes, int n_in,
                              void* d_out, int out_size, void* d_ws, size_t ws_size,
                              hipStream_t stream) {
    (void)in_sizes; (void)n_in; (void)out_size; (void)ws_size;
    const float* A = (const float*)d_in[0];   // fp32 [65536][512]
    const float* W = (const float*)d_in[1];   // fp32 [512][2048]
    float* out     = (float*)d_out;           // fp32 [64][32][64]

    uint8_t* ws = (uint8_t*)d_ws;
    const size_t AROW_B = (size_t)B_SZ * D_IN * 4;              // 128 KiB
    const size_t OUTS_B = (size_t)B_SZ * NC * DC * 4;           // 512 KiB
    const size_t G_B    = (size_t)B_SZ * D_IN * NC * 4;         // 4 MiB
    float* Arow = (float*)ws;
    float* outs = (float*)(ws + AROW_B);
    float* G    = (float*)(ws + AROW_B + OUTS_B);
    float* Mp   = (float*)(ws + AROW_B + OUTS_B + G_B);         // 16 MiB

    // iteration 0: uniform c  ==  (1/32) * rowsum(A) . W, then squash
    hipMemsetAsync(Arow, 0, AROW_B, stream);
    rowsum_kernel<<<512, 256, 0, stream>>>(A, Arow);
    s0_squash<<<512, 256, 0, stream>>>(Arow, W, outs);

    // iterations 1 and 2: factored routing, one A pass each, no u_hat
    for (int it = 0; it < 2; ++it) {
        g_kernel<<<256, 256, 0, stream>>>(W, outs, G);
        routing_pass<<<256, 256, 0, stream>>>(A, G, Mp);
        s_squash<<<2048, 64, 0, stream>>>(Mp, W, outs, it == 1 ? out : nullptr);
    }
}

// Round 6
// 660.409 us; speedup vs baseline: 1.2595x; 1.2595x over previous
//
#include <hip/hip_runtime.h>

// Problem constants
#define B_SZ   64
#define N_IN   1024
#define D_IN   512
#define NC     32
#define DC     64

typedef unsigned short u16;
typedef unsigned short u16x8 __attribute__((ext_vector_type(8)));

__device__ __forceinline__ float bf2f(u16 u) {
    unsigned x = ((unsigned)u) << 16;
    return __builtin_bit_cast(float, x);
}
__device__ __forceinline__ u16 f2bf(float f) {
    unsigned x = __builtin_bit_cast(unsigned, f);
    unsigned r = (x + 0x7fffu + ((x >> 16) & 1u)) >> 16;   // RNE
    return (u16)r;
}

#define ASYNC_LDS16(g, l) __builtin_amdgcn_global_load_lds( \
    (const __attribute__((address_space(1))) void*)(g),     \
    (__attribute__((address_space(3))) void*)(l), 16, 0, 0)

// ---------------------------------------------------------------------------
// conv_rowsum: Ab[b,i,k] = bf16(A[b,i,k]);  Arow[b][k] = sum_i A[b,i,k] (fp32)
// grid 512 = 64 b x 8 chunks of 128 rows. Thread owns k-pair; coalesced.
// ---------------------------------------------------------------------------
__global__ __launch_bounds__(256) void conv_rowsum(const float* __restrict__ A,
                                                   u16* __restrict__ Ab,
                                                   float* __restrict__ Arow) {
    const int tid = threadIdx.x;
    const int b  = blockIdx.x >> 3;
    const int r0 = (blockIdx.x & 7) << 7;
    const size_t base = ((size_t)(b * N_IN + r0)) * 512 + tid * 2;
    const float* p = A + base;
    u16* q = Ab + base;
    float a0 = 0.f, a1 = 0.f;
    for (int r = 0; r < 128; ++r) {
        float2 v = *(const float2*)(p + (size_t)r * 512);
        a0 += v.x; a1 += v.y;
        unsigned pk = (unsigned)f2bf(v.x) | ((unsigned)f2bf(v.y) << 16);
        *(unsigned*)(q + (size_t)r * 512) = pk;
    }
    atomicAdd(&Arow[b * 512 + tid * 2], a0);
    atomicAdd(&Arow[b * 512 + tid * 2 + 1], a1);
}

// ---------------------------------------------------------------------------
// s0 + squash: s[b][z] = (1/32) sum_k Arow[b][k] W[k][z]; squash over d.
// ---------------------------------------------------------------------------
__global__ __launch_bounds__(256) void s0_squash(const float* __restrict__ Arow,
                                                 const float* __restrict__ W,
                                                 float* __restrict__ outs) {
    const int tid = threadIdx.x;
    const int b  = blockIdx.x >> 3;
    const int z0 = (blockIdx.x & 7) << 8;
    const int z  = z0 + tid;
    const float* ar = Arow + b * 512;          // uniform -> s_load
    float acc = 0.f;
#pragma unroll 8
    for (int k = 0; k < 512; ++k) acc += ar[k] * W[(size_t)k * 2048 + z];
    acc *= 0.03125f;
    float sq = acc * acc;
    for (int off = 32; off; off >>= 1) sq += __shfl_xor(sq, off);
    float o = acc * (1.0f / sqrtf(sq + 1e-7f));
    outs[(size_t)b * 2048 + z] = o;
}

// ---------------------------------------------------------------------------
// G-kernel: G[b][k][n] = sum_d W[k][n*64+d] * outs[b][n*64+d]
// ---------------------------------------------------------------------------
__global__ __launch_bounds__(256) void g_kernel(const float* __restrict__ W,
                                                const float* __restrict__ outs,
                                                float* __restrict__ G) {
    const int tid  = threadIdx.x;
    const int b    = blockIdx.x >> 2;
    const int q    = blockIdx.x & 3;
    const int w    = __builtin_amdgcn_readfirstlane(tid >> 6);
    const int lane = tid & 63;
    const int kp   = lane >> 5;
    const int n    = lane & 31;

    float4 vr[16];
#pragma unroll
    for (int i = 0; i < 16; ++i)
        vr[i] = *(const float4*)(outs + (size_t)b * 2048 + n * 64 + i * 4);

    const int kbase = q * 128 + w * 32 + kp;
    for (int jj = 0; jj < 16; ++jj) {
        const int k = kbase + jj * 2;
        const float* wr = W + (size_t)k * 2048 + n * 64;
        float acc = 0.f;
#pragma unroll
        for (int dq = 0; dq < 16; ++dq) {
            float4 wv = *(const float4*)(wr + dq * 4);
            acc += wv.x * vr[dq].x + wv.y * vr[dq].y + wv.z * vr[dq].z + wv.w * vr[dq].w;
        }
        G[(size_t)b * 16384 + k * 32 + n] = acc;
    }
}

// ---------------------------------------------------------------------------
// routing_pass: grid 1024 = 64 b x 16 chunks of 64 rows; block = one chunk.
// Stage bf16 rows via global_load_lds w/ row-XOR chunk swizzle (conflict-free
// b128 reads). phase1: lane=row, wave=n-oct, G via uniform s_loads. softmax
// in LDS. phase2: lane=k-chunk, wave=n-oct; Mp[b][chunk][32][512] written.
// ---------------------------------------------------------------------------
__global__ __launch_bounds__(256, 2) void routing_pass(const u16* __restrict__ Ab,
                                                       const float* __restrict__ G,
                                                       float* __restrict__ Mp) {
    __shared__ u16   Al[64 * 512];      // 64 KiB
    __shared__ float cl[64 * 36];       // 9 KiB
    const int tid   = threadIdx.x;
    const int lane  = tid & 63;
    const int w     = __builtin_amdgcn_readfirstlane(tid >> 6);
    const int b     = blockIdx.x >> 4;
    const int chunk = blockIdx.x & 15;
    const int row0  = chunk * 64;

    // ---- stage: wave w loads rows w*16 .. w*16+15, swizzled source chunks
    const size_t rowbase = (size_t)(b * N_IN + row0);
#pragma unroll
    for (int rr = 0; rr < 16; ++rr) {
        const int r   = w * 16 + rr;
        const int sig = (lane & 56) | ((lane & 7) ^ (r & 7));
        const u16* src = Ab + (rowbase + r) * 512 + sig * 8;
        ASYNC_LDS16(src, &Al[r * 512]);
    }
    __syncthreads();

    // ---- phase1: logits[row=lane][n-oct w] ----
    float lacc[8];
#pragma unroll
    for (int nn = 0; nn < 8; ++nn) lacc[nn] = 0.f;
    const float* Gb = G + (size_t)b * 16384 + w * 8;
    const u16* arow = Al + lane * 512;
    const int rx = lane & 7;
    for (int c = 0; c < 64; ++c) {
        const int cs = (c & 56) | ((c & 7) ^ rx);
        u16x8 a8 = *(const u16x8*)&arow[cs * 8];
        const float* g = Gb + c * 256;            // uniform -> s_load
#pragma unroll
        for (int e = 0; e < 8; ++e) {
            float a = bf2f(a8[e]);
#pragma unroll
            for (int nn = 0; nn < 8; ++nn)
                lacc[nn] += a * g[e * 32 + nn];
        }
    }
#pragma unroll
    for (int nn = 0; nn < 8; ++nn) cl[lane * 36 + w * 8 + nn] = lacc[nn];
    __syncthreads();

    // ---- softmax over 32 capsules per row ----
    if (tid < 64) {
        float* row = &cl[tid * 36];
        float mx = row[0];
        for (int k = 1; k < NC; ++k) mx = fmaxf(mx, row[k]);
        float ssum = 0.f;
        for (int k = 0; k < NC; ++k) { float t = __expf(row[k] - mx); row[k] = t; ssum += t; }
        float inv = 1.f / ssum;
        for (int k = 0; k < NC; ++k) row[k] *= inv;
    }
    __syncthreads();

    // ---- phase2: Mp[n = w*8+j][k = lane*8+e] = sum_r c[r][n] * A[r][k] ----
    float acc[8][8];
#pragma unroll
    for (int j = 0; j < 8; ++j)
#pragma unroll
        for (int e = 0; e < 8; ++e) acc[j][e] = 0.f;

    for (int r = 0; r < 64; ++r) {
        const int cs = (lane & 56) | ((lane & 7) ^ (r & 7));
        u16x8 a8 = *(const u16x8*)&Al[r * 512 + cs * 8];
        float4 c0 = *(const float4*)&cl[r * 36 + w * 8];       // broadcast
        float4 c1 = *(const float4*)&cl[r * 36 + w * 8 + 4];
        float cv[8] = {c0.x, c0.y, c0.z, c0.w, c1.x, c1.y, c1.z, c1.w};
#pragma unroll
        for (int e = 0; e < 8; ++e) {
            float a = bf2f(a8[e]);
#pragma unroll
            for (int j = 0; j < 8; ++j) acc[j][e] += cv[j] * a;
        }
    }

    float* mpb = Mp + (((size_t)b * 16 + chunk) * 32) * 512;
#pragma unroll
    for (int j = 0; j < 8; ++j) {
        const int n = w * 8 + j;
        float4 s0 = {acc[j][0], acc[j][1], acc[j][2], acc[j][3]};
        float4 s1 = {acc[j][4], acc[j][5], acc[j][6], acc[j][7]};
        float* dst = mpb + (size_t)n * 512 + lane * 8;
        *(float4*)dst       = s0;
        *(float4*)(dst + 4) = s1;
    }
}

// ---------------------------------------------------------------------------
// s_squash: M = sum of 16 Mp slices; s[b,n,d] = sum_k M[k] W[k][n*64+d];
// squash over d; write outs (and final out on last iteration).
// ---------------------------------------------------------------------------
__global__ __launch_bounds__(64) void s_squash(const float* __restrict__ Mp,
                                               const float* __restrict__ W,
                                               float* __restrict__ outs,
                                               float* __restrict__ outf) {
    __shared__ float Ml[512];
    const int b = blockIdx.x >> 5;
    const int n = blockIdx.x & 31;
    const int d = threadIdx.x;

    {
        float4 s0 = {0, 0, 0, 0}, s1 = {0, 0, 0, 0};
#pragma unroll
        for (int c = 0; c < 16; ++c) {
            const float* p = Mp + (((size_t)b * 16 + c) * 32 + n) * 512 + d * 8;
            float4 v0 = *(const float4*)p;
            float4 v1 = *(const float4*)(p + 4);
            s0.x += v0.x; s0.y += v0.y; s0.z += v0.z; s0.w += v0.w;
            s1.x += v1.x; s1.y += v1.y; s1.z += v1.z; s1.w += v1.w;
        }
        *(float4*)&Ml[d * 8]     = s0;
        *(float4*)&Ml[d * 8 + 4] = s1;
    }
    __syncthreads();

    const float* wc = W + n * 64 + d;
    float acc = 0.f;
#pragma unroll 8
    for (int k = 0; k < 512; ++k) acc += Ml[k] * wc[(size_t)k * 2048];

    float sq = acc * acc;
    for (int off = 32; off; off >>= 1) sq += __shfl_xor(sq, off);
    float o = acc * (1.0f / sqrtf(sq + 1e-7f));
    size_t idx = (size_t)b * 2048 + n * 64 + d;
    outs[idx] = o;
    if (outf) outf[idx] = o;
}

// ---------------------------------------------------------------------------
extern "C" void kernel_launch(void* const* d_in, const int* in_sizes, int n_in,
                              void* d_out, int out_size, void* d_ws, size_t ws_size,
                              hipStream_t stream) {
    (void)in_sizes; (void)n_in; (void)out_size; (void)ws_size;
    const float* A = (const float*)d_in[0];   // fp32 [65536][512]
    const float* W = (const float*)d_in[1];   // fp32 [512][2048]
    float* out     = (float*)d_out;           // fp32 [64][32][64]

    uint8_t* ws = (uint8_t*)d_ws;
    const size_t AB_B   = (size_t)B_SZ * N_IN * D_IN * 2;        // 64 MiB
    const size_t AROW_B = (size_t)B_SZ * D_IN * 4;               // 128 KiB
    const size_t OUTS_B = (size_t)B_SZ * NC * DC * 4;            // 512 KiB
    const size_t G_B    = (size_t)B_SZ * D_IN * NC * 4;          // 4 MiB
    u16*   Ab   = (u16*)ws;
    float* Arow = (float*)(ws + AB_B);
    float* outs = (float*)(ws + AB_B + AROW_B);
    float* G    = (float*)(ws + AB_B + AROW_B + OUTS_B);
    float* Mp   = (float*)(ws + AB_B + AROW_B + OUTS_B + G_B);   // 64 MiB

    // iteration 0: uniform c == (1/32) * rowsum(A) . W  (fused w/ bf16 convert)
    hipMemsetAsync(Arow, 0, AROW_B, stream);
    conv_rowsum<<<512, 256, 0, stream>>>(A, Ab, Arow);
    s0_squash<<<512, 256, 0, stream>>>(Arow, W, outs);

    // iterations 1 and 2: factored routing, one bf16-A pass each
    for (int it = 0; it < 2; ++it) {
        g_kernel<<<256, 256, 0, stream>>>(W, outs, G);
        routing_pass<<<1024, 256, 0, stream>>>(Ab, G, Mp);
        s_squash<<<2048, 64, 0, stream>>>(Mp, W, outs, it == 1 ? out : nullptr);
    }
}

// Round 7
// 399.510 us; speedup vs baseline: 2.0821x; 1.6530x over previous
//
#include <hip/hip_runtime.h>

// Problem constants
#define B_SZ   64
#define N_IN   1024
#define D_IN   512
#define NC     32
#define DC     64

typedef unsigned short u16;
typedef __bf16 bf16x8 __attribute__((ext_vector_type(8)));
typedef unsigned short u16x8 __attribute__((ext_vector_type(8)));
typedef float f32x4  __attribute__((ext_vector_type(4)));
typedef float f32x16 __attribute__((ext_vector_type(16)));

__device__ __forceinline__ float bf2f(u16 u) {
    unsigned x = ((unsigned)u) << 16;
    return __builtin_bit_cast(float, x);
}
__device__ __forceinline__ u16 f2bf(float f) {
    unsigned x = __builtin_bit_cast(unsigned, f);
    unsigned r = (x + 0x7fffu + ((x >> 16) & 1u)) >> 16;   // RNE
    return (u16)r;
}

#define ASYNC_LDS16(g, l) __builtin_amdgcn_global_load_lds( \
    (const __attribute__((address_space(1))) void*)(g),     \
    (__attribute__((address_space(3))) void*)(l), 16, 0, 0)

// ---------------------------------------------------------------------------
// conv_rowsum: Ab = bf16(A); Arow[b][k] = sum_i A[b,i,k]. (verified R6)
// ---------------------------------------------------------------------------
__global__ __launch_bounds__(256) void conv_rowsum(const float* __restrict__ A,
                                                   u16* __restrict__ Ab,
                                                   float* __restrict__ Arow) {
    const int tid = threadIdx.x;
    const int b  = blockIdx.x >> 3;
    const int r0 = (blockIdx.x & 7) << 7;
    const size_t base = ((size_t)(b * N_IN + r0)) * 512 + tid * 2;
    const float* p = A + base;
    u16* q = Ab + base;
    float a0 = 0.f, a1 = 0.f;
    for (int r = 0; r < 128; ++r) {
        float2 v = *(const float2*)(p + (size_t)r * 512);
        a0 += v.x; a1 += v.y;
        unsigned pk = (unsigned)f2bf(v.x) | ((unsigned)f2bf(v.y) << 16);
        *(unsigned*)(q + (size_t)r * 512) = pk;
    }
    atomicAdd(&Arow[b * 512 + tid * 2], a0);
    atomicAdd(&Arow[b * 512 + tid * 2 + 1], a1);
}

// ---------------------------------------------------------------------------
// s0_squash (b-batched 4x): s[b][z] = (1/32) Arow[b].W[:,z]; squash; -> outs
// grid (8 z-tiles, 16 b-groups)
// ---------------------------------------------------------------------------
__global__ __launch_bounds__(256) void s0_squash(const float* __restrict__ Arow,
                                                 const float* __restrict__ W,
                                                 float* __restrict__ outs) {
    const int tid = threadIdx.x;
    const int z   = blockIdx.x * 256 + tid;
    const int bg  = blockIdx.y * 4;
    float acc[4] = {};
    for (int k = 0; k < 512; ++k) {
        float wv = W[(size_t)k * 2048 + z];
#pragma unroll
        for (int bb = 0; bb < 4; ++bb)
            acc[bb] += Arow[(bg + bb) * 512 + k] * wv;   // uniform -> s_load
    }
#pragma unroll
    for (int bb = 0; bb < 4; ++bb) {
        float v = acc[bb] * 0.03125f;
        float sq = v * v;
        for (int off = 32; off; off >>= 1) sq += __shfl_xor(sq, off);
        outs[(size_t)(bg + bb) * 2048 + z] = v * (1.0f / sqrtf(sq + 1e-7f));
    }
}

// ---------------------------------------------------------------------------
// g_pack: Gpack[b][kk][n][kq] = bf16( sum_d W[kk*32+kq][n*64+d] * outs[b][n*64+d] )
// W read exactly once (4 MiB). grid (32 k-tiles of 16, 16 n-pairs).
// Thread = (k-slot = tid>>4, b-slot = tid&15, 4 b's each).
// ---------------------------------------------------------------------------
__global__ __launch_bounds__(256) void g_pack(const float* __restrict__ W,
                                              const float* __restrict__ outs,
                                              u16* __restrict__ Gpack) {
    __shared__ float vl[64 * 130];          // [b][2n x 64d], pad->130
    const int tid = threadIdx.x;
    const int kt  = blockIdx.x;
    const int np  = blockIdx.y;

    for (int t = tid; t < 8192; t += 256) {
        int b = t >> 7, idx = t & 127;
        vl[b * 130 + idx] = outs[(size_t)b * 2048 + np * 128 + idx];
    }
    __syncthreads();

    const int bs = tid & 15;
    const int k  = kt * 16 + (tid >> 4);
    float acc[4][2] = {};
    for (int n2 = 0; n2 < 2; ++n2) {
        const float* wr = W + (size_t)k * 2048 + (np * 2 + n2) * 64;
        for (int d = 0; d < 64; ++d) {
            float wv = wr[d];                                  // 16 lanes share addr
#pragma unroll
            for (int bb = 0; bb < 4; ++bb)
                acc[bb][n2] += wv * vl[(bs + 16 * bb) * 130 + n2 * 64 + d];
        }
    }
    const int kk = k >> 5, kq = k & 31;
#pragma unroll
    for (int bb = 0; bb < 4; ++bb)
#pragma unroll
        for (int n2 = 0; n2 < 2; ++n2) {
            int b = bs + 16 * bb, n = np * 2 + n2;
            Gpack[(((size_t)b * 16 + kk) * 32 + n) * 32 + kq] = f2bf(acc[bb][n2]);
        }
}

// ---------------------------------------------------------------------------
// routing_mfma: grid 1024 = 64 b x 16 chunks of 64 rows.
// Stage Ab rows (XOR-swizzled, verified R6). phase1: logits via 16x16x32 bf16
// MFMA (A from LDS, B = Gpack global). softmax (stride-33 cl, conflict-free).
// phase2: Mp = c^T x Ab via 32x32x16 bf16 MFMA. Slot-consistent operand
// packing on both phases (HW k-permutation cancels).
// ---------------------------------------------------------------------------
__global__ __launch_bounds__(256, 2) void routing_mfma(const u16* __restrict__ Ab,
                                                       const u16* __restrict__ Gpack,
                                                       float* __restrict__ Mp) {
    __shared__ u16   Al[64 * 512];      // 64 KiB
    __shared__ float cl[64 * 33];       // 8.25 KiB
    const int tid   = threadIdx.x;
    const int lane  = tid & 63;
    const int w     = __builtin_amdgcn_readfirstlane(tid >> 6);
    const int b     = blockIdx.x >> 4;
    const int chunk = blockIdx.x & 15;
    const int row0  = chunk * 64;

    // ---- stage 64 rows, swizzled chunks (R6-verified pattern) ----
    const size_t rowbase = (size_t)(b * N_IN + row0);
#pragma unroll
    for (int rr = 0; rr < 16; ++rr) {
        const int r   = w * 16 + rr;
        const int sig = (lane & 56) | ((lane & 7) ^ (r & 7));
        ASYNC_LDS16(Ab + (rowbase + r) * 512 + sig * 8, &Al[r * 512]);
    }
    __syncthreads();

    // ---- phase1: logits[64 r][32 n] via mfma 16x16x32; wave w = m-tile ----
    const int quad = lane >> 4;
    const int l16  = lane & 15;
    f32x4 lacc[2] = {};
    const u16* gb = Gpack + (size_t)b * 16384;
    {
        const int r  = w * 16 + l16;
        const u16* ar = &Al[r * 512];
        for (int kk = 0; kk < 16; ++kk) {
            const int c  = kk * 4 + quad;
            const int cs = (c & 56) | ((c & 7) ^ (r & 7));
            bf16x8 af = *(const bf16x8*)&ar[cs * 8];
#pragma unroll
            for (int nt = 0; nt < 2; ++nt) {
                bf16x8 bf = *(const bf16x8*)&gb[(kk * 32 + nt * 16 + l16) * 32 + quad * 8];
                lacc[nt] = __builtin_amdgcn_mfma_f32_16x16x32_bf16(af, bf, lacc[nt], 0, 0, 0);
            }
        }
    }
#pragma unroll
    for (int nt = 0; nt < 2; ++nt)
#pragma unroll
        for (int reg = 0; reg < 4; ++reg)
            cl[(w * 16 + quad * 4 + reg) * 33 + nt * 16 + l16] = lacc[nt][reg];
    __syncthreads();

    // ---- softmax over 32 capsules per row (stride 33: conflict-free) ----
    if (tid < 64) {
        float* row = &cl[tid * 33];
        float mx = row[0];
        for (int k = 1; k < NC; ++k) mx = fmaxf(mx, row[k]);
        float ssum = 0.f;
        for (int k = 0; k < NC; ++k) { float t = __expf(row[k] - mx); row[k] = t; ssum += t; }
        float inv = 1.f / ssum;
        for (int k = 0; k < NC; ++k) row[k] *= inv;
    }
    __syncthreads();

    // ---- phase2: Mp[32 n][512 k] = c^T x Ab via mfma 32x32x16 ----
    const int h   = lane >> 5;
    const int l32 = lane & 31;
    bf16x8 cfrag[4];
#pragma unroll
    for (int kk2 = 0; kk2 < 4; ++kk2) {
        u16x8 t;
#pragma unroll
        for (int j = 0; j < 8; ++j)
            t[j] = f2bf(cl[(kk2 * 16 + h * 8 + j) * 33 + l32]);
        cfrag[kk2] = __builtin_bit_cast(bf16x8, t);
    }
    float* mpb = Mp + ((size_t)b * 16 + chunk) * 32 * 512;
    for (int cti = 0; cti < 4; ++cti) {
        const int ct   = w * 4 + cti;
        const int kcol = ct * 32 + l32;
        const int c2   = kcol >> 3;
        const int e    = kcol & 7;
        f32x16 acc = {};
#pragma unroll
        for (int kk2 = 0; kk2 < 4; ++kk2) {
            u16x8 t;
#pragma unroll
            for (int j = 0; j < 8; ++j) {
                const int r2  = kk2 * 16 + h * 8 + j;
                const int cs2 = (c2 & 56) | ((c2 & 7) ^ (r2 & 7));
                t[j] = Al[r2 * 512 + cs2 * 8 + e];
            }
            bf16x8 bf = __builtin_bit_cast(bf16x8, t);
            acc = __builtin_amdgcn_mfma_f32_32x32x16_bf16(cfrag[kk2], bf, acc, 0, 0, 0);
        }
#pragma unroll
        for (int reg = 0; reg < 16; ++reg) {
            const int n = (reg & 3) + 8 * (reg >> 2) + 4 * h;
            mpb[(size_t)n * 512 + kcol] = acc[reg];
        }
    }
}

// ---------------------------------------------------------------------------
// s_final: Ml[b][k] = sum_ch Mp; s[b,n,d] = sum_k Ml W[k][n*64+d]; squash.
// grid (32 n, 8 b-groups of 8). W n-slice staged bf16 in LDS (64 KiB);
// coalesced reads, W traffic 32 MiB total.
// ---------------------------------------------------------------------------
__global__ __launch_bounds__(256, 2) void s_final(const float* __restrict__ Mp,
                                                  const float* __restrict__ W,
                                                  float* __restrict__ outs,
                                                  float* __restrict__ outf) {
    __shared__ u16   Wl[512 * 64];      // 64 KiB bf16
    __shared__ float Ml[8 * 512];       // 16 KiB
    const int tid = threadIdx.x;
    const int n   = blockIdx.x;
    const int bg  = blockIdx.y * 8;

    for (int t = tid; t < 32768; t += 256) {
        int k = t >> 6, d = t & 63;
        Wl[t] = f2bf(W[(size_t)k * 2048 + n * 64 + d]);
    }
    for (int t = tid; t < 4096; t += 256) {
        int bs = t >> 9, k = t & 511;
        const float* p = Mp + (((size_t)(bg + bs) * 16) * 32 + n) * 512 + k;
        float s = 0.f;
#pragma unroll
        for (int ch = 0; ch < 16; ++ch) s += p[(size_t)ch * 32 * 512];
        Ml[t] = s;
    }
    __syncthreads();

    const int w = tid >> 6;
    const int d = tid & 63;
    float acc[2] = {};
    for (int k = 0; k < 512; ++k) {
        float wv = bf2f(Wl[k * 64 + d]);
        acc[0] += Ml[(w * 2) * 512 + k] * wv;       // broadcast
        acc[1] += Ml[(w * 2 + 1) * 512 + k] * wv;
    }
#pragma unroll
    for (int i = 0; i < 2; ++i) {
        const int b = bg + w * 2 + i;
        float sq = acc[i] * acc[i];
        for (int off = 32; off; off >>= 1) sq += __shfl_xor(sq, off);
        float o = acc[i] * (1.0f / sqrtf(sq + 1e-7f));
        size_t idx = (size_t)b * 2048 + n * 64 + d;
        outs[idx] = o;
        if (outf) outf[idx] = o;
    }
}

// ---------------------------------------------------------------------------
extern "C" void kernel_launch(void* const* d_in, const int* in_sizes, int n_in,
                              void* d_out, int out_size, void* d_ws, size_t ws_size,
                              hipStream_t stream) {
    (void)in_sizes; (void)n_in; (void)out_size; (void)ws_size;
    const float* A = (const float*)d_in[0];   // fp32 [65536][512]
    const float* W = (const float*)d_in[1];   // fp32 [512][2048]
    float* out     = (float*)d_out;           // fp32 [64][32][64]

    uint8_t* ws = (uint8_t*)d_ws;
    const size_t AB_B    = (size_t)B_SZ * N_IN * D_IN * 2;          // 64 MiB
    const size_t AROW_B  = (size_t)B_SZ * D_IN * 4;                 // 128 KiB
    const size_t OUTS_B  = (size_t)B_SZ * NC * DC * 4;              // 512 KiB
    const size_t GP_B    = (size_t)B_SZ * 16 * 32 * 32 * 2;         // 2 MiB
    u16*   Ab    = (u16*)ws;
    float* Arow  = (float*)(ws + AB_B);
    float* outs  = (float*)(ws + AB_B + AROW_B);
    u16*   Gpack = (u16*)(ws + AB_B + AROW_B + OUTS_B);
    float* Mp    = (float*)(ws + AB_B + AROW_B + OUTS_B + GP_B);    // 64 MiB

    // iteration 0: uniform c == (1/32) rowsum(A) . W (fused with bf16 convert)
    hipMemsetAsync(Arow, 0, AROW_B, stream);
    conv_rowsum<<<512, 256, 0, stream>>>(A, Ab, Arow);
    s0_squash<<<dim3(8, 16), 256, 0, stream>>>(Arow, W, outs);

    // iterations 1 and 2
    for (int it = 0; it < 2; ++it) {
        g_pack<<<dim3(32, 16), 256, 0, stream>>>(W, outs, Gpack);
        routing_mfma<<<1024, 256, 0, stream>>>(Ab, Gpack, Mp);
        s_final<<<dim3(32, 8), 256, 0, stream>>>(Mp, W, outs, it == 1 ? out : nullptr);
    }
}